// Round 8
// baseline (150.923 us; speedup 1.0000x reference)
//
#include <hip/hip_runtime.h>
#include <cstdint>
#include <cstddef>

typedef float f32x4 __attribute__((ext_vector_type(4)));
typedef __bf16 bf16x8 __attribute__((ext_vector_type(8)));
typedef __bf16 bf16x2 __attribute__((ext_vector_type(2)));
typedef uint32_t u32x4 __attribute__((ext_vector_type(4)));

#define TSS 9216
#define VST 9344  // vqk row stride (bf16). 9344*2 = 0x4900 B: k*0x900 mod 0x1000 walks all 16
                  // 256-B channel-bit values -> TCC channels spread (9216*2=0x4800 hit only 2/16)
#define KST 104   // attn LDS row stride (bf16)
#define XST 72    // proj X^T LDS row stride (bf16)
#define WST 72    // out_proj W-chunk row stride (bf16)
#define RSTD 68   // out_proj A-chunk row stride in DWORDS

__device__ __forceinline__ uint32_t pack2bf(float a, float b) {
  bf16x2 v = { (__bf16)a, (__bf16)b };   // native v_cvt_pk_bf16_f32 (RNE)
  return __builtin_bit_cast(uint32_t, v);
}

// ---------------- Kernel 0: W fp32 -> bf16 (L2-resident operand for proj) ----------------
__global__ __launch_bounds__(256, 8) void wcvt_kernel(
    const float* __restrict__ w, uint16_t* __restrict__ wbf)
{
  const int i = blockIdx.x * 256 + threadIdx.x;   // 24576 float4 = 1536*64 floats
  const float4 v = ((const float4*)w)[i];
  ((uint2*)wbf)[i] = uint2{pack2bf(v.x, v.y), pack2bf(v.z, v.w)};
}

// ---------------- Kernel 1: vqk[b][o][p] = sum_c W[o][c] X[b][c][p] + bias[o] ----------------
// Strip-persistent: block = (b, 32-wide p strip). X^T staged once; A-frags in regs all block.
// Wave w covers 24 o-tiles; W B-frags direct from L2-hot bf16 W, 3-deep prefetch ring.
__global__ __launch_bounds__(256, 4) void proj_kernel(
    const float* __restrict__ x, const uint16_t* __restrict__ wbf,
    const float* __restrict__ b_vkq, uint16_t* __restrict__ vqk)
{
  __shared__ __align__(16) uint16_t Bt[32 * XST];  // X^T tile [p][c]

  const int t   = threadIdx.x;
  const int blk = blockIdx.x;        // 1152 = 4b * 288 nt
  const int nt  = blk % 288;
  const int b   = blk / 288;
  const int n0  = nt * 32;

  {
    const float* __restrict__ xb = x + (size_t)b * 64 * TSS + n0;
    const int p  = t & 31;
    const int c0 = (t >> 5) * 8;
    float v[8];
    #pragma unroll
    for (int i = 0; i < 8; ++i) v[i] = xb[(size_t)(c0 + i) * TSS + p];
    *(uint4*)&Bt[p * XST + c0] =
      uint4{pack2bf(v[0], v[1]), pack2bf(v[2], v[3]),
            pack2bf(v[4], v[5]), pack2bf(v[6], v[7])};
  }
  __syncthreads();

  const int L    = t & 63;
  const int w    = t >> 6;
  const int lcol = L & 15;
  const int lq   = L >> 4;

  bf16x8 af[2][2];
  #pragma unroll
  for (int tm = 0; tm < 2; ++tm)
    #pragma unroll
    for (int ks = 0; ks < 2; ++ks)
      af[tm][ks] = *(const bf16x8*)&Bt[(tm*16 + lcol) * XST + ks*32 + lq*8];

  const int obase = w * 384;

  // preload all 24 biases (b_vkq is 6 KB, L2-hot)
  float bias[24];
  #pragma unroll
  for (int ot = 0; ot < 24; ++ot) bias[ot] = b_vkq[obase + ot*16 + lcol];

  // 3-deep W prefetch ring
  bf16x8 bw[3][2];
  #pragma unroll
  for (int pre = 0; pre < 3; ++pre) {
    const int o = obase + pre*16 + lcol;
    #pragma unroll
    for (int ks = 0; ks < 2; ++ks)
      bw[pre][ks] = *(const bf16x8*)(wbf + (size_t)o * 64 + ks*32 + lq*8);
  }

  #pragma unroll 3
  for (int ot = 0; ot < 24; ++ot) {
    const int s = ot % 3;
    const int o = obase + ot*16 + lcol;
    f32x4 acc[2];
    acc[0] = f32x4{bias[ot], bias[ot], bias[ot], bias[ot]};
    acc[1] = acc[0];
    #pragma unroll
    for (int tm = 0; tm < 2; ++tm)
      #pragma unroll
      for (int ks = 0; ks < 2; ++ks)
        acc[tm] = __builtin_amdgcn_mfma_f32_16x16x32_bf16(af[tm][ks], bw[s][ks], acc[tm], 0, 0, 0);
    if (ot < 21) {
      const int on = obase + (ot + 3)*16 + lcol;
      #pragma unroll
      for (int ks = 0; ks < 2; ++ks)
        bw[s][ks] = *(const bf16x8*)(wbf + (size_t)on * 64 + ks*32 + lq*8);
    }
    uint16_t* __restrict__ dst = vqk + (size_t)(b * 1536 + o) * VST + n0;
    #pragma unroll
    for (int tm = 0; tm < 2; ++tm)
      *(uint2*)(dst + tm*16 + lq*4) =
        uint2{pack2bf(acc[tm][0], acc[tm][1]), pack2bf(acc[tm][2], acc[tm][3])};
  }
}

// ---------------- Kernel 2: per-(b,hc) attention, D[z][x] form ----------------
__global__ __launch_bounds__(384, 5) void attn_kernel(uint16_t* __restrict__ vqk)
{
  __shared__ __align__(16) uint16_t Ks[96 * KST];  // K; reused for P after scores
  __shared__ __align__(16) uint16_t Qs[96 * KST];

  const int t   = threadIdx.x;
  const int blk = blockIdx.x;
  const int b   = blk >> 9;
  const int hc  = blk & 511;
  const size_t pbase = (size_t)(b * 1536 + hc) * VST;
  const uint16_t* __restrict__ vplane = vqk + pbase;
  const uint16_t* __restrict__ kplane = vqk + pbase + (size_t)1024 * VST;
  const uint16_t* __restrict__ qplane = vqk + pbase + (size_t)512  * VST;

  {
    const uint4* __restrict__ sk = (const uint4*)kplane;
    const uint4* __restrict__ sq = (const uint4*)qplane;
    #pragma unroll
    for (int i = 0; i < 3; ++i) {
      const int g   = t + i * 384;
      const int row = g / 12;
      const int off = (g - row * 12) * 8;
      *(uint4*)&Ks[row * KST + off] = sk[g];
      *(uint4*)&Qs[row * KST + off] = sq[g];
    }
  }

  const int L    = t & 63;
  const int w    = t / 64;
  const int lcol = L & 15;
  const int lq   = L >> 4;
  const int xrow = 16 * w + lcol;
  const float C  = 1.44269504088896f / 9216.0f;
  const f32x4 zero4 = {0.f, 0.f, 0.f, 0.f};

  bf16x8 bv[3];
  #pragma unroll
  for (int ks = 0; ks < 3; ++ks)
    bv[ks] = *(const bf16x8*)(vplane + (size_t)xrow * 96 + ks*32 + lq*8);

  __syncthreads();

  f32x4 sa[6];
  #pragma unroll
  for (int i = 0; i < 6; ++i) sa[i] = zero4;
  #pragma unroll
  for (int tz = 0; tz < 6; ++tz)
    #pragma unroll
    for (int ks = 0; ks < 3; ++ks) {
      const bf16x8 ak = *(const bf16x8*)&Ks[(tz*16 + lcol) * KST + ks*32 + lq*8];
      sa[tz] = __builtin_amdgcn_mfma_f32_16x16x32_bf16(ak, bv[ks], sa[tz], 0, 0, 0);
    }

  // |s/9216| <= 0.007 -> max-subtraction safely dropped
  float s = 0.f;
  #pragma unroll
  for (int tz = 0; tz < 6; ++tz)
    #pragma unroll
    for (int r = 0; r < 4; ++r)
      s += __builtin_exp2f(sa[tz][r] * C);
  s += __shfl_xor(s, 16, 64);
  s += __shfl_xor(s, 32, 64);
  const float inv = 1.0f / s;

  __syncthreads();   // all waves done reading Ks -> overwrite with P

  #pragma unroll
  for (int tz = 0; tz < 6; ++tz) {
    const float p0 = __builtin_exp2f(sa[tz][0] * C) * inv;
    const float p1 = __builtin_exp2f(sa[tz][1] * C) * inv;
    const float p2 = __builtin_exp2f(sa[tz][2] * C) * inv;
    const float p3 = __builtin_exp2f(sa[tz][3] * C) * inv;
    *(uint2*)&Ks[xrow * KST + tz*16 + lq*4] = uint2{pack2bf(p0, p1), pack2bf(p2, p3)};
  }

  bf16x8 bp[3];
  #pragma unroll
  for (int ks = 0; ks < 3; ++ks)
    bp[ks] = *(const bf16x8*)&Ks[xrow * KST + ks*32 + lq*8];
  f32x4 oa[6];
  #pragma unroll
  for (int i = 0; i < 6; ++i) oa[i] = zero4;
  #pragma unroll
  for (int tz = 0; tz < 6; ++tz)
    #pragma unroll
    for (int ks = 0; ks < 3; ++ks) {
      const bf16x8 aq = *(const bf16x8*)&Qs[(tz*16 + lcol) * KST + ks*32 + lq*8];
      oa[tz] = __builtin_amdgcn_mfma_f32_16x16x32_bf16(aq, bp[ks], oa[tz], 0, 0, 0);
    }

  uint16_t* __restrict__ dst = vqk + pbase;
  #pragma unroll
  for (int tz = 0; tz < 6; ++tz)
    *(uint2*)(dst + (size_t)xrow * 96 + tz*16 + lq*4) =
      uint2{pack2bf(oa[tz][0], oa[tz][1]), pack2bf(oa[tz][2], oa[tz][3])};
}

// ---------------- Kernel 3 (MFMA GEMM): out[b][o][p] = b_out[o] + sum_k W'[o][k] A[k][p] ------
__global__ __launch_bounds__(256, 4) void out_proj_kernel(
    const uint16_t* __restrict__ attn, const float* __restrict__ w_out,
    const float* __restrict__ b_out, float* __restrict__ out)
{
  __shared__ __align__(16) uint32_t As2[2][32 * RSTD];
  __shared__ __align__(16) uint16_t Wl[2][64 * WST];

  const int t    = threadIdx.x;
  const int blk  = blockIdx.x;          // 576 = 4b * 144 nt
  const int nt   = blk % 144;
  const int b    = blk / 144;
  const int n0   = nt * 64;
  const int L    = t & 63;
  const int w    = t >> 6;
  const int lcol = L & 15;
  const int lq   = L >> 4;
  const int kp_g = t >> 4;
  const int seg  = t & 15;

  const uint16_t* __restrict__ ab = attn + (size_t)b * 1536 * VST;

  uint2  pa[2][2];
  float4 pw[4];

  auto load_chunk = [&](int k0) {
    #pragma unroll
    for (int i = 0; i < 2; ++i) {
      const int kp = kp_g + i * 16;
      const int ke = k0 + 2*kp, ko = ke + 1;
      const int pe = ((ke & 7) << 6) | (ke >> 3);
      const int po = ((ko & 7) << 6) | (ko >> 3);
      pa[i][0] = *(const uint2*)(ab + (size_t)pe * VST + n0 + seg * 4);
      pa[i][1] = *(const uint2*)(ab + (size_t)po * VST + n0 + seg * 4);
    }
    #pragma unroll
    for (int i = 0; i < 4; ++i) {
      const int idx = t + i * 256;
      pw[i] = *(const float4*)(w_out + (size_t)(idx >> 4) * 512 + k0 + (idx & 15) * 4);
    }
  };

  auto store_chunk = [&](int buf) {
    #pragma unroll
    for (int i = 0; i < 2; ++i) {
      const int kp = kp_g + i * 16;
      const uint2 a = pa[i][0], bb = pa[i][1];
      uint4 d;
      d.x = (a.x & 0xffffu) | (bb.x << 16);
      d.y = (a.x >> 16)     | (bb.x & 0xffff0000u);
      d.z = (a.y & 0xffffu) | (bb.y << 16);
      d.w = (a.y >> 16)     | (bb.y & 0xffff0000u);
      *(uint4*)&As2[buf][kp * RSTD + seg * 4] = d;
    }
    #pragma unroll
    for (int i = 0; i < 4; ++i) {
      const int idx = t + i * 256;
      const float4 v = pw[i];
      *(uint2*)&Wl[buf][(idx >> 4) * WST + (idx & 15) * 4] =
        uint2{pack2bf(v.x, v.y), pack2bf(v.z, v.w)};
    }
  };

  f32x4 acc[4];
  const f32x4 zero4 = {0.f, 0.f, 0.f, 0.f};
  #pragma unroll
  for (int tm = 0; tm < 4; ++tm) acc[tm] = zero4;

  load_chunk(0);

  for (int c = 0; c < 8; ++c) {
    const int buf = c & 1;
    store_chunk(buf);
    if (c < 7) load_chunk((c + 1) * 64);
    __syncthreads();
    #pragma unroll
    for (int ks = 0; ks < 2; ++ks) {
      u32x4 bb;
      #pragma unroll
      for (int jj = 0; jj < 4; ++jj)
        bb[jj] = As2[buf][(ks*16 + lq*4 + jj) * RSTD + w*16 + lcol];
      const bf16x8 bfr = __builtin_bit_cast(bf16x8, bb);
      #pragma unroll
      for (int tm = 0; tm < 4; ++tm) {
        const bf16x8 af = *(const bf16x8*)&Wl[buf][(tm*16 + lcol) * WST + ks*32 + lq*8];
        acc[tm] = __builtin_amdgcn_mfma_f32_16x16x32_bf16(af, bfr, acc[tm], 0, 0, 0);
      }
    }
  }

  const int p = n0 + w*16 + lcol;
  #pragma unroll
  for (int tm = 0; tm < 4; ++tm)
    #pragma unroll
    for (int r = 0; r < 4; ++r) {
      const int o = tm*16 + lq*4 + r;
      out[(size_t)(b * 64 + o) * TSS + p] = acc[tm][r] + b_out[o];
    }
}

extern "C" void kernel_launch(void* const* d_in, const int* in_sizes, int n_in,
                              void* d_out, int out_size, void* d_ws, size_t ws_size,
                              hipStream_t stream) {
  const float* x     = (const float*)d_in[0];
  const float* w_vkq = (const float*)d_in[1];
  const float* b_vkq = (const float*)d_in[2];
  const float* w_out = (const float*)d_in[3];
  const float* b_out = (const float*)d_in[4];
  float* out = (float*)d_out;
  uint16_t* vqk = (uint16_t*)d_ws;                 // 4*1536*9344 bf16 = 114.8 MB (padded stride)
  uint16_t* wbf = vqk + (size_t)4*1536*VST;        // +196 KB bf16 W

  wcvt_kernel<<<dim3(96), dim3(256), 0, stream>>>(w_vkq, wbf);
  proj_kernel<<<dim3(1152), dim3(256), 0, stream>>>(x, wbf, b_vkq, vqk);
  attn_kernel<<<dim3(2048), dim3(384), 0, stream>>>(vqk);
  out_proj_kernel<<<dim3(576), dim3(256), 0, stream>>>(vqk, w_out, b_out, out);
}

// Round 10
// 149.253 us; speedup vs baseline: 1.0112x; 1.0112x over previous
//
#include <hip/hip_runtime.h>
#include <cstdint>
#include <cstddef>

typedef float f32x4 __attribute__((ext_vector_type(4)));
typedef float f32x2 __attribute__((ext_vector_type(2)));
typedef __bf16 bf16x8 __attribute__((ext_vector_type(8)));
typedef __bf16 bf16x2 __attribute__((ext_vector_type(2)));
typedef uint32_t u32x4 __attribute__((ext_vector_type(4)));

#define TSS 9216
#define VST 9344  // O-plane row stride (bf16 elements)
#define VSF 9472  // fp8 plane stride (bytes), 16B-multiple
#define KSB 104   // attn K LDS row stride (BYTES, fp8)
#define KST 104   // attn Q/P LDS row stride (uint16 elements)
#define XST 72    // proj X^T LDS row stride (bf16)
#define WST 72    // out_proj W-chunk row stride (bf16)
#define RSTD 68   // out_proj A-chunk row stride in DWORDS

#define FP8_SCALE 32.0f   // V,Q,K stored as fp8 of 32*value (kills denormal flush)

__device__ __forceinline__ uint32_t pack2bf(float a, float b) {
  bf16x2 v = { (__bf16)a, (__bf16)b };   // native v_cvt_pk_bf16_f32 (RNE)
  return __builtin_bit_cast(uint32_t, v);
}
__device__ __forceinline__ uint32_t pack4fp8(float a, float b, float c, float d) {
  uint32_t r = __builtin_amdgcn_cvt_pk_fp8_f32(a, b, 0, false);
  return (uint32_t)__builtin_amdgcn_cvt_pk_fp8_f32(c, d, (int)r, true);
}
// 4 packed fp8 -> 4 bf16 (with scale)
__device__ __forceinline__ uint2 fp8x4_to_bf16x4(uint32_t v, float scale) {
  const f32x2 lo = __builtin_amdgcn_cvt_pk_f32_fp8((int)v, false);
  const f32x2 hi = __builtin_amdgcn_cvt_pk_f32_fp8((int)v, true);
  return uint2{pack2bf(lo[0] * scale, lo[1] * scale),
               pack2bf(hi[0] * scale, hi[1] * scale)};
}

// ---------------- Kernel 0: W fp32 -> bf16 * 32 (folds fp8 scale into proj) ----------------
__global__ __launch_bounds__(256, 8) void wcvt_kernel(
    const float* __restrict__ w, uint16_t* __restrict__ wbf)
{
  const int i = blockIdx.x * 256 + threadIdx.x;   // 24576 float4 = 1536*64 floats
  const float4 v = ((const float4*)w)[i];
  ((uint2*)wbf)[i] = uint2{pack2bf(v.x * FP8_SCALE, v.y * FP8_SCALE),
                           pack2bf(v.z * FP8_SCALE, v.w * FP8_SCALE)};
}

// ---------------- Kernel 1: projection -> fp8 V/Q/K planes (values pre-scaled x32) ----------
__global__ __launch_bounds__(256, 4) void proj_kernel(
    const float* __restrict__ x, const uint16_t* __restrict__ wbf,
    const float* __restrict__ b_vkq,
    uint8_t* __restrict__ Vr, uint8_t* __restrict__ Qr, uint8_t* __restrict__ Kr)
{
  __shared__ __align__(16) uint16_t Bt[64 * XST];  // X^T tile [p][c] bf16

  const int t   = threadIdx.x;
  const int blk = blockIdx.x;        // 576 = 4b * 144 nt
  const int nt  = blk % 144;
  const int b   = blk / 144;
  const int n0  = nt * 64;

  {
    const float* __restrict__ xb = x + (size_t)b * 64 * TSS + n0;
    const int p  = t & 63;
    const int c0 = (t >> 6) * 16;
    float v[16];
    #pragma unroll
    for (int i = 0; i < 16; ++i) v[i] = xb[(size_t)(c0 + i) * TSS + p];
    #pragma unroll
    for (int h = 0; h < 2; ++h)
      *(uint4*)&Bt[p * XST + c0 + h*8] =
        uint4{pack2bf(v[h*8+0], v[h*8+1]), pack2bf(v[h*8+2], v[h*8+3]),
              pack2bf(v[h*8+4], v[h*8+5]), pack2bf(v[h*8+6], v[h*8+7])};
  }
  __syncthreads();

  const int L    = t & 63;
  const int w    = t >> 6;
  const int lcol = L & 15;
  const int lq   = L >> 4;

  bf16x8 af[4][2];   // A = X^T, m = p (4 tiles of 16)
  #pragma unroll
  for (int tm = 0; tm < 4; ++tm)
    #pragma unroll
    for (int ks = 0; ks < 2; ++ks)
      af[tm][ks] = *(const bf16x8*)&Bt[(tm*16 + lcol) * XST + ks*32 + lq*8];

  const int obase = w * 384;

  bf16x8 bw[3][2];
  float  bias_r[3];
  #pragma unroll
  for (int pre = 0; pre < 3; ++pre) {
    const int o = obase + pre*16 + lcol;
    #pragma unroll
    for (int ks = 0; ks < 2; ++ks)
      bw[pre][ks] = *(const bf16x8*)(wbf + (size_t)o * 64 + ks*32 + lq*8);
    bias_r[pre] = b_vkq[o] * FP8_SCALE;
  }

  for (int ot = 0; ot < 24; ++ot) {
    const int s3  = ot % 3;
    const int o   = obase + ot*16 + lcol;
    const float bias = bias_r[s3];
    f32x4 acc[4];
    #pragma unroll
    for (int tm = 0; tm < 4; ++tm) acc[tm] = f32x4{bias, bias, bias, bias};
    #pragma unroll
    for (int tm = 0; tm < 4; ++tm)
      #pragma unroll
      for (int ks = 0; ks < 2; ++ks)
        acc[tm] = __builtin_amdgcn_mfma_f32_16x16x32_bf16(af[tm][ks], bw[s3][ks], acc[tm], 0, 0, 0);
    if (ot < 21) {
      const int on = obase + (ot + 3)*16 + lcol;
      #pragma unroll
      for (int ks = 0; ks < 2; ++ks)
        bw[s3][ks] = *(const bf16x8*)(wbf + (size_t)on * 64 + ks*32 + lq*8);
      bias_r[s3] = b_vkq[on] * FP8_SCALE;
    }
    // region: o in [0,512)=V, [512,1024)=Q, [1024,1536)=K
    const int sreg = (obase + ot*16) >> 9;
    uint8_t* __restrict__ reg = (sreg == 0) ? Vr : ((sreg == 1) ? Qr : Kr);
    const size_t pbase = (size_t)(b * 512 + (o & 511)) * VSF + n0;
    #pragma unroll
    for (int tm = 0; tm < 4; ++tm)
      *(uint32_t*)(reg + pbase + tm*16 + lq*4) =
        pack4fp8(acc[tm][0], acc[tm][1], acc[tm][2], acc[tm][3]);
  }
}

// ---------------- Kernel 2: attention. Scores fp8 MFMA; P bf16 LDS; PV bf16 MFMA ------------
// 384 threads = 6 waves; wave w owns x-rows [16w,16w+16). K fp8 in LDS (P bf16 unions over
// it after a barrier); Q upconverted fp8->bf16 at staging; V read per-wave from global.
__global__ __launch_bounds__(384, 4) void attn_kernel(
    const uint8_t* __restrict__ Vr, const uint8_t* __restrict__ Qr,
    const uint8_t* __restrict__ Kr, uint16_t* __restrict__ Obuf)
{
  __shared__ __align__(16) uint8_t  KP[96 * 208];  // K fp8 (stride KSB); then P bf16 (stride KST u16)
  __shared__ __align__(16) uint16_t Qs[96 * KST];  // Q bf16

  const int t   = threadIdx.x;
  const int blk = blockIdx.x;
  const int b   = blk >> 9;
  const int hc  = blk & 511;
  const size_t pb8 = (size_t)(b * 512 + hc) * VSF;
  const uint8_t* __restrict__ vplane = Vr + pb8;
  const float qscale = 1.0f / FP8_SCALE;

  // stage K (fp8, 576 uint4) and Q (fp8 -> bf16)
  {
    const uint4* __restrict__ sk = (const uint4*)(Kr + pb8);
    const uint4* __restrict__ sq = (const uint4*)(Qr + pb8);
    #pragma unroll
    for (int half = 0; half < 2; ++half) {
      const int g = t + half * 384;
      if (half == 0 || t < 192) {
        const int row = g / 6, seg = g % 6;
        *(uint4*)&KP[row * KSB + seg * 16] = sk[g];
        const uint4 q4 = sq[g];
        uint16_t* d = &Qs[row * KST + seg * 16];
        *(uint4*)(d + 0) = __builtin_bit_cast(uint4,
            uint4{fp8x4_to_bf16x4(q4.x, qscale).x, fp8x4_to_bf16x4(q4.x, qscale).y,
                  fp8x4_to_bf16x4(q4.y, qscale).x, fp8x4_to_bf16x4(q4.y, qscale).y});
        *(uint4*)(d + 8) = __builtin_bit_cast(uint4,
            uint4{fp8x4_to_bf16x4(q4.z, qscale).x, fp8x4_to_bf16x4(q4.z, qscale).y,
                  fp8x4_to_bf16x4(q4.w, qscale).x, fp8x4_to_bf16x4(q4.w, qscale).y});
      }
    }
  }

  const int L    = t & 63;
  const int w    = t / 64;
  const int lcol = L & 15;
  const int lq   = L >> 4;
  const int xrow = 16 * w + lcol;
  // scores carry FP8_SCALE^2 = 1024x; fold into exp2 constant
  const float C  = 1.44269504088896f / (9216.0f * (FP8_SCALE * FP8_SCALE));
  const f32x4 zero4 = {0.f, 0.f, 0.f, 0.f};

  // V B-frags straight from global (own rows only): 8 consecutive fp8 = one b64
  long bv[3];
  #pragma unroll
  for (int ks = 0; ks < 3; ++ks)
    bv[ks] = *(const long*)(vplane + (size_t)xrow * 96 + ks*32 + lq*8);

  __syncthreads();

  // scores D[z][x]: A = K z-tiles, B = V x-rows (fp8 MFMA)
  f32x4 sa[6];
  #pragma unroll
  for (int i = 0; i < 6; ++i) sa[i] = zero4;
  #pragma unroll
  for (int tz = 0; tz < 6; ++tz)
    #pragma unroll
    for (int ks = 0; ks < 3; ++ks) {
      const long ak = *(const long*)&KP[(tz*16 + lcol) * KSB + ks*32 + lq*8];
      sa[tz] = __builtin_amdgcn_mfma_f32_16x16x32_fp8_fp8(ak, bv[ks], sa[tz], 0, 0, 0);
    }

  // softmax over z (|s_true| <= 0.007 -> max-subtraction safely dropped)
  float s = 0.f;
  #pragma unroll
  for (int tz = 0; tz < 6; ++tz)
    #pragma unroll
    for (int r = 0; r < 4; ++r)
      s += __builtin_exp2f(sa[tz][r] * C);
  s += __shfl_xor(s, 16, 64);
  s += __shfl_xor(s, 32, 64);
  const float inv = 1.0f / s;

  __syncthreads();   // all waves done reading K -> overwrite region with P (bf16)

  uint16_t* __restrict__ Ps = (uint16_t*)KP;
  #pragma unroll
  for (int tz = 0; tz < 6; ++tz) {
    const float p0 = __builtin_exp2f(sa[tz][0] * C) * inv;
    const float p1 = __builtin_exp2f(sa[tz][1] * C) * inv;
    const float p2 = __builtin_exp2f(sa[tz][2] * C) * inv;
    const float p3 = __builtin_exp2f(sa[tz][3] * C) * inv;
    *(uint2*)&Ps[xrow * KST + tz*16 + lq*4] = uint2{pack2bf(p0, p1), pack2bf(p2, p3)};
  }

  // PV D[z'][x]: A = Q z'-tiles (bf16), B = P x-rows (own-wave LDS; DS in-order per wave)
  bf16x8 bp[3];
  #pragma unroll
  for (int ks = 0; ks < 3; ++ks)
    bp[ks] = *(const bf16x8*)&Ps[xrow * KST + ks*32 + lq*8];
  f32x4 oa[6];
  #pragma unroll
  for (int i = 0; i < 6; ++i) oa[i] = zero4;
  #pragma unroll
  for (int tz = 0; tz < 6; ++tz)
    #pragma unroll
    for (int ks = 0; ks < 3; ++ks) {
      const bf16x8 aq = *(const bf16x8*)&Qs[(tz*16 + lcol) * KST + ks*32 + lq*8];
      oa[tz] = __builtin_amdgcn_mfma_f32_16x16x32_bf16(aq, bp[ks], oa[tz], 0, 0, 0);
    }

  // store O[x][z'] bf16; 4 consecutive z' per lane -> dwordx2
  uint16_t* __restrict__ dst = Obuf + (size_t)(b * 512 + hc) * VST;
  #pragma unroll
  for (int tz = 0; tz < 6; ++tz)
    *(uint2*)(dst + (size_t)xrow * 96 + tz*16 + lq*4) =
      uint2{pack2bf(oa[tz][0], oa[tz][1]), pack2bf(oa[tz][2], oa[tz][3])};
}

// ---------------- Kernel 3 (MFMA GEMM): out[b][o][p] = b_out[o] + sum_k W'[o][k] O[pl(k)][p] --
__global__ __launch_bounds__(256, 4) void out_proj_kernel(
    const uint16_t* __restrict__ Obuf, const float* __restrict__ w_out,
    const float* __restrict__ b_out, float* __restrict__ out)
{
  __shared__ __align__(16) uint32_t As2[2][32 * RSTD];
  __shared__ __align__(16) uint16_t Wl[2][64 * WST];

  const int t    = threadIdx.x;
  const int blk  = blockIdx.x;          // 576 = 4b * 144 nt
  const int nt   = blk % 144;
  const int b    = blk / 144;
  const int n0   = nt * 64;
  const int L    = t & 63;
  const int w    = t >> 6;
  const int lcol = L & 15;
  const int lq   = L >> 4;
  const int kp_g = t >> 4;
  const int seg  = t & 15;

  const uint16_t* __restrict__ ab = Obuf + (size_t)b * 512 * VST;

  uint2  pa[2][2];
  float4 pw[4];

  auto load_chunk = [&](int k0) {
    #pragma unroll
    for (int i = 0; i < 2; ++i) {
      const int kp = kp_g + i * 16;
      const int ke = k0 + 2*kp, ko = ke + 1;
      const int pe = ((ke & 7) << 6) | (ke >> 3);
      const int po = ((ko & 7) << 6) | (ko >> 3);
      pa[i][0] = *(const uint2*)(ab + (size_t)pe * VST + n0 + seg * 4);
      pa[i][1] = *(const uint2*)(ab + (size_t)po * VST + n0 + seg * 4);
    }
    #pragma unroll
    for (int i = 0; i < 4; ++i) {
      const int idx = t + i * 256;
      pw[i] = *(const float4*)(w_out + (size_t)(idx >> 4) * 512 + k0 + (idx & 15) * 4);
    }
  };

  auto store_chunk = [&](int buf) {
    #pragma unroll
    for (int i = 0; i < 2; ++i) {
      const int kp = kp_g + i * 16;
      const uint2 a = pa[i][0], bb = pa[i][1];
      uint4 d;
      d.x = (a.x & 0xffffu) | (bb.x << 16);
      d.y = (a.x >> 16)     | (bb.x & 0xffff0000u);
      d.z = (a.y & 0xffffu) | (bb.y << 16);
      d.w = (a.y >> 16)     | (bb.y & 0xffff0000u);
      *(uint4*)&As2[buf][kp * RSTD + seg * 4] = d;
    }
    #pragma unroll
    for (int i = 0; i < 4; ++i) {
      const int idx = t + i * 256;
      const float4 v = pw[i];
      *(uint2*)&Wl[buf][(idx >> 4) * WST + (idx & 15) * 4] =
        uint2{pack2bf(v.x, v.y), pack2bf(v.z, v.w)};
    }
  };

  f32x4 acc[4];
  const f32x4 zero4 = {0.f, 0.f, 0.f, 0.f};
  #pragma unroll
  for (int tm = 0; tm < 4; ++tm) acc[tm] = zero4;

  load_chunk(0);

  for (int c = 0; c < 8; ++c) {
    const int buf = c & 1;
    store_chunk(buf);
    if (c < 7) load_chunk((c + 1) * 64);
    __syncthreads();
    #pragma unroll
    for (int ks = 0; ks < 2; ++ks) {
      u32x4 bb;
      #pragma unroll
      for (int jj = 0; jj < 4; ++jj)
        bb[jj] = As2[buf][(ks*16 + lq*4 + jj) * RSTD + w*16 + lcol];
      const bf16x8 bfr = __builtin_bit_cast(bf16x8, bb);
      #pragma unroll
      for (int tm = 0; tm < 4; ++tm) {
        const bf16x8 af = *(const bf16x8*)&Wl[buf][(tm*16 + lcol) * WST + ks*32 + lq*8];
        acc[tm] = __builtin_amdgcn_mfma_f32_16x16x32_bf16(af, bfr, acc[tm], 0, 0, 0);
      }
    }
  }

  const int p = n0 + w*16 + lcol;
  #pragma unroll
  for (int tm = 0; tm < 4; ++tm)
    #pragma unroll
    for (int r = 0; r < 4; ++r) {
      const int o = tm*16 + lq*4 + r;
      out[(size_t)(b * 64 + o) * TSS + p] = acc[tm][r] + b_out[o];
    }
}

extern "C" void kernel_launch(void* const* d_in, const int* in_sizes, int n_in,
                              void* d_out, int out_size, void* d_ws, size_t ws_size,
                              hipStream_t stream) {
  const float* x     = (const float*)d_in[0];
  const float* w_vkq = (const float*)d_in[1];
  const float* b_vkq = (const float*)d_in[2];
  const float* w_out = (const float*)d_in[3];
  const float* b_out = (const float*)d_in[4];
  float* out = (float*)d_out;

  uint16_t* Obuf = (uint16_t*)d_ws;                         // 2048*9344*2 = 38.3 MB (bf16 O)
  uint8_t*  Vr   = (uint8_t*)(Obuf + (size_t)2048 * VST);   // 3 fp8 regions, 19.4 MB each
  uint8_t*  Qr   = Vr + (size_t)2048 * VSF;
  uint8_t*  Kr   = Qr + (size_t)2048 * VSF;
  uint16_t* wbf  = (uint16_t*)(Kr + (size_t)2048 * VSF);    // 196 KB bf16 W (x32 pre-scaled)

  wcvt_kernel<<<dim3(96), dim3(256), 0, stream>>>(w_vkq, wbf);
  proj_kernel<<<dim3(576), dim3(256), 0, stream>>>(x, wbf, b_vkq, Vr, Qr, Kr);
  attn_kernel<<<dim3(2048), dim3(384), 0, stream>>>(Vr, Qr, Kr, Obuf);
  out_proj_kernel<<<dim3(576), dim3(256), 0, stream>>>(Obuf, w_out, b_out, out);
}

// Round 11
// 123.213 us; speedup vs baseline: 1.2249x; 1.2113x over previous
//
#include <hip/hip_runtime.h>
#include <cstdint>
#include <cstddef>

typedef float f32x4 __attribute__((ext_vector_type(4)));
typedef float f32x2 __attribute__((ext_vector_type(2)));
typedef __bf16 bf16x8 __attribute__((ext_vector_type(8)));
typedef __bf16 bf16x2 __attribute__((ext_vector_type(2)));
typedef uint32_t u32x4 __attribute__((ext_vector_type(4)));

#define TSS 9216
#define VST 9344  // O-plane row stride (bf16 elements)
#define VSF 9472  // fp8 plane stride (bytes), 16B-multiple
#define KSB 104   // attn K LDS row stride (BYTES, fp8)
#define KST 104   // attn Q/P LDS row stride (uint16 elements)
#define XST 72    // proj X^T LDS row stride (bf16)
#define WST 72    // out_proj W-chunk row stride (bf16)
#define RSTD 68   // out_proj A-chunk row stride in DWORDS
#define EPS 68    // proj epilogue LDS row stride (BYTES): 17 dwords, conflict-free transpose

#define FP8_SCALE 32.0f   // V,Q,K stored as fp8 of 32*value (kills denormal flush)

__device__ __forceinline__ uint32_t pack2bf(float a, float b) {
  bf16x2 v = { (__bf16)a, (__bf16)b };   // native v_cvt_pk_bf16_f32 (RNE)
  return __builtin_bit_cast(uint32_t, v);
}
__device__ __forceinline__ uint32_t pack4fp8(float a, float b, float c, float d) {
  uint32_t r = __builtin_amdgcn_cvt_pk_fp8_f32(a, b, 0, false);
  return (uint32_t)__builtin_amdgcn_cvt_pk_fp8_f32(c, d, (int)r, true);
}
// 4 packed fp8 -> 4 bf16 (with scale)
__device__ __forceinline__ uint2 fp8x4_to_bf16x4(uint32_t v, float scale) {
  const f32x2 lo = __builtin_amdgcn_cvt_pk_f32_fp8((int)v, false);
  const f32x2 hi = __builtin_amdgcn_cvt_pk_f32_fp8((int)v, true);
  return uint2{pack2bf(lo[0] * scale, lo[1] * scale),
               pack2bf(hi[0] * scale, hi[1] * scale)};
}

// ---------------- Kernel 0: W fp32 -> bf16 * 32 (folds fp8 scale into proj) ----------------
__global__ __launch_bounds__(256, 8) void wcvt_kernel(
    const float* __restrict__ w, uint16_t* __restrict__ wbf)
{
  const int i = blockIdx.x * 256 + threadIdx.x;   // 24576 float4 = 1536*64 floats
  const float4 v = ((const float4*)w)[i];
  ((uint2*)wbf)[i] = uint2{pack2bf(v.x * FP8_SCALE, v.y * FP8_SCALE),
                           pack2bf(v.z * FP8_SCALE, v.w * FP8_SCALE)};
}

// ---------------- Kernel 1: projection -> fp8 V/Q/K planes (values pre-scaled x32) ----------
// Block = (b, 64-wide p strip, o-quarter); 2304 blocks -> ~16 resident waves/CU (latency
// hiding; R10's 576-block version stalled 96% at 4 waves/CU). Wave w covers 6 o-tiles.
// Epilogue: D[p][o] -> fp8 -> per-wave LDS transpose (no barrier) -> full 64-B row stores.
__global__ __launch_bounds__(256, 4) void proj_kernel(
    const float* __restrict__ x, const uint16_t* __restrict__ wbf,
    const float* __restrict__ b_vkq,
    uint8_t* __restrict__ Vr, uint8_t* __restrict__ Qr, uint8_t* __restrict__ Kr)
{
  __shared__ __align__(16) uint16_t Bt[64 * XST];      // X^T tile [p][c] bf16 (9.2 KB)
  __shared__ __align__(16) uint8_t  Ep[4][16 * EPS];   // per-wave transpose scratch (4.3 KB)

  const int t   = threadIdx.x;
  const int blk = blockIdx.x;        // 2304 = (4b * 144 nt) * 4 oq ; oq fastest -> share X-tile
  const int oq  = blk & 3;
  const int bn  = blk >> 2;
  const int nt  = bn % 144;
  const int b   = bn / 144;
  const int n0  = nt * 64;

  {
    const float* __restrict__ xb = x + (size_t)b * 64 * TSS + n0;
    const int p  = t & 63;
    const int c0 = (t >> 6) * 16;
    float v[16];
    #pragma unroll
    for (int i = 0; i < 16; ++i) v[i] = xb[(size_t)(c0 + i) * TSS + p];
    #pragma unroll
    for (int h = 0; h < 2; ++h)
      *(uint4*)&Bt[p * XST + c0 + h*8] =
        uint4{pack2bf(v[h*8+0], v[h*8+1]), pack2bf(v[h*8+2], v[h*8+3]),
              pack2bf(v[h*8+4], v[h*8+5]), pack2bf(v[h*8+6], v[h*8+7])};
  }
  __syncthreads();

  const int L    = t & 63;
  const int w    = t >> 6;
  const int lcol = L & 15;
  const int lq   = L >> 4;

  bf16x8 af[4][2];   // A = X^T, m = p (4 tiles of 16) — invariant all 6 o-tiles
  #pragma unroll
  for (int tm = 0; tm < 4; ++tm)
    #pragma unroll
    for (int ks = 0; ks < 2; ++ks)
      af[tm][ks] = *(const bf16x8*)&Bt[(tm*16 + lcol) * XST + ks*32 + lq*8];

  const int obase = oq * 384 + w * 96;   // wave's 6 o-tiles

  bf16x8 bw[3][2];
  float  bias_r[3];
  #pragma unroll
  for (int pre = 0; pre < 3; ++pre) {
    const int o = obase + pre*16 + lcol;
    #pragma unroll
    for (int ks = 0; ks < 2; ++ks)
      bw[pre][ks] = *(const bf16x8*)(wbf + (size_t)o * 64 + ks*32 + lq*8);
    bias_r[pre] = b_vkq[o] * FP8_SCALE;
  }

  uint8_t* __restrict__ ep = Ep[w];

  #pragma unroll
  for (int ot = 0; ot < 6; ++ot) {
    const int s3   = ot % 3;
    const float bias = bias_r[s3];
    f32x4 acc[4];
    #pragma unroll
    for (int tm = 0; tm < 4; ++tm) acc[tm] = f32x4{bias, bias, bias, bias};
    #pragma unroll
    for (int tm = 0; tm < 4; ++tm)
      #pragma unroll
      for (int ks = 0; ks < 2; ++ks)
        acc[tm] = __builtin_amdgcn_mfma_f32_16x16x32_bf16(af[tm][ks], bw[s3][ks], acc[tm], 0, 0, 0);
    if (ot < 3) {
      const int on = obase + (ot + 3)*16 + lcol;
      #pragma unroll
      for (int ks = 0; ks < 2; ++ks)
        bw[s3][ks] = *(const bf16x8*)(wbf + (size_t)on * 64 + ks*32 + lq*8);
      bias_r[s3] = b_vkq[on] * FP8_SCALE;
    }
    // transpose D[p][o] -> [o][p] through wave-private LDS (in-order per wave, no barrier)
    #pragma unroll
    for (int tm = 0; tm < 4; ++tm)
      *(uint32_t*)&ep[lcol * EPS + tm*16 + lq*4] =
        pack4fp8(acc[tm][0], acc[tm][1], acc[tm][2], acc[tm][3]);

    const int o_t  = obase + ot * 16;
    const int sreg = o_t >> 9;   // 0=V 1=Q 2=K (16-tile never straddles a 512 boundary)
    uint8_t* __restrict__ reg = (sreg == 0) ? Vr : ((sreg == 1) ? Qr : Kr);
    const size_t rb = (size_t)(b * 512 + (o_t & 511)) * VSF + n0;
    #pragma unroll
    for (int s = 0; s < 4; ++s) {
      const int orow = s*4 + lq;
      const uint32_t d = *(const uint32_t*)&ep[orow * EPS + lcol*4];
      *(uint32_t*)(reg + rb + (size_t)orow * VSF + lcol*4) = d;   // 4 full 64-B rows / instr
    }
  }
}

// ---------------- Kernel 2: attention. Scores fp8 MFMA; P bf16 LDS; PV bf16 MFMA ------------
// 384 threads = 6 waves; wave w owns x-rows [16w,16w+16). K fp8 in LDS (P bf16 unions over
// it after a barrier); Q upconverted fp8->bf16 at staging; V read per-wave from global.
__global__ __launch_bounds__(384, 4) void attn_kernel(
    const uint8_t* __restrict__ Vr, const uint8_t* __restrict__ Qr,
    const uint8_t* __restrict__ Kr, uint16_t* __restrict__ Obuf)
{
  __shared__ __align__(16) uint8_t  KP[96 * 208];  // K fp8 (stride KSB); then P bf16 (stride KST u16)
  __shared__ __align__(16) uint16_t Qs[96 * KST];  // Q bf16

  const int t   = threadIdx.x;
  const int blk = blockIdx.x;
  const int b   = blk >> 9;
  const int hc  = blk & 511;
  const size_t pb8 = (size_t)(b * 512 + hc) * VSF;
  const uint8_t* __restrict__ vplane = Vr + pb8;
  const float qscale = 1.0f / FP8_SCALE;

  // stage K (fp8, 576 uint4) and Q (fp8 -> bf16)
  {
    const uint4* __restrict__ sk = (const uint4*)(Kr + pb8);
    const uint4* __restrict__ sq = (const uint4*)(Qr + pb8);
    #pragma unroll
    for (int half = 0; half < 2; ++half) {
      const int g = t + half * 384;
      if (half == 0 || t < 192) {
        const int row = g / 6, seg = g % 6;
        *(uint4*)&KP[row * KSB + seg * 16] = sk[g];
        const uint4 q4 = sq[g];
        uint16_t* d = &Qs[row * KST + seg * 16];
        *(uint4*)(d + 0) = __builtin_bit_cast(uint4,
            uint4{fp8x4_to_bf16x4(q4.x, qscale).x, fp8x4_to_bf16x4(q4.x, qscale).y,
                  fp8x4_to_bf16x4(q4.y, qscale).x, fp8x4_to_bf16x4(q4.y, qscale).y});
        *(uint4*)(d + 8) = __builtin_bit_cast(uint4,
            uint4{fp8x4_to_bf16x4(q4.z, qscale).x, fp8x4_to_bf16x4(q4.z, qscale).y,
                  fp8x4_to_bf16x4(q4.w, qscale).x, fp8x4_to_bf16x4(q4.w, qscale).y});
      }
    }
  }

  const int L    = t & 63;
  const int w    = t / 64;
  const int lcol = L & 15;
  const int lq   = L >> 4;
  const int xrow = 16 * w + lcol;
  // scores carry FP8_SCALE^2 = 1024x; fold into exp2 constant
  const float C  = 1.44269504088896f / (9216.0f * (FP8_SCALE * FP8_SCALE));
  const f32x4 zero4 = {0.f, 0.f, 0.f, 0.f};

  // V B-frags straight from global (own rows only): 8 consecutive fp8 = one b64
  long bv[3];
  #pragma unroll
  for (int ks = 0; ks < 3; ++ks)
    bv[ks] = *(const long*)(vplane + (size_t)xrow * 96 + ks*32 + lq*8);

  __syncthreads();

  // scores D[z][x]: A = K z-tiles, B = V x-rows (fp8 MFMA)
  f32x4 sa[6];
  #pragma unroll
  for (int i = 0; i < 6; ++i) sa[i] = zero4;
  #pragma unroll
  for (int tz = 0; tz < 6; ++tz)
    #pragma unroll
    for (int ks = 0; ks < 3; ++ks) {
      const long ak = *(const long*)&KP[(tz*16 + lcol) * KSB + ks*32 + lq*8];
      sa[tz] = __builtin_amdgcn_mfma_f32_16x16x32_fp8_fp8(ak, bv[ks], sa[tz], 0, 0, 0);
    }

  // softmax over z (|s_true| <= 0.007 -> max-subtraction safely dropped)
  float s = 0.f;
  #pragma unroll
  for (int tz = 0; tz < 6; ++tz)
    #pragma unroll
    for (int r = 0; r < 4; ++r)
      s += __builtin_exp2f(sa[tz][r] * C);
  s += __shfl_xor(s, 16, 64);
  s += __shfl_xor(s, 32, 64);
  const float inv = 1.0f / s;

  __syncthreads();   // all waves done reading K -> overwrite region with P (bf16)

  uint16_t* __restrict__ Ps = (uint16_t*)KP;
  #pragma unroll
  for (int tz = 0; tz < 6; ++tz) {
    const float p0 = __builtin_exp2f(sa[tz][0] * C) * inv;
    const float p1 = __builtin_exp2f(sa[tz][1] * C) * inv;
    const float p2 = __builtin_exp2f(sa[tz][2] * C) * inv;
    const float p3 = __builtin_exp2f(sa[tz][3] * C) * inv;
    *(uint2*)&Ps[xrow * KST + tz*16 + lq*4] = uint2{pack2bf(p0, p1), pack2bf(p2, p3)};
  }

  // PV D[z'][x]: A = Q z'-tiles (bf16), B = P x-rows (own-wave LDS; DS in-order per wave)
  bf16x8 bp[3];
  #pragma unroll
  for (int ks = 0; ks < 3; ++ks)
    bp[ks] = *(const bf16x8*)&Ps[xrow * KST + ks*32 + lq*8];
  f32x4 oa[6];
  #pragma unroll
  for (int i = 0; i < 6; ++i) oa[i] = zero4;
  #pragma unroll
  for (int tz = 0; tz < 6; ++tz)
    #pragma unroll
    for (int ks = 0; ks < 3; ++ks) {
      const bf16x8 aq = *(const bf16x8*)&Qs[(tz*16 + lcol) * KST + ks*32 + lq*8];
      oa[tz] = __builtin_amdgcn_mfma_f32_16x16x32_bf16(aq, bp[ks], oa[tz], 0, 0, 0);
    }

  // store O[x][z'] bf16; 4 consecutive z' per lane -> dwordx2
  uint16_t* __restrict__ dst = Obuf + (size_t)(b * 512 + hc) * VST;
  #pragma unroll
  for (int tz = 0; tz < 6; ++tz)
    *(uint2*)(dst + (size_t)xrow * 96 + tz*16 + lq*4) =
      uint2{pack2bf(oa[tz][0], oa[tz][1]), pack2bf(oa[tz][2], oa[tz][3])};
}

// ---------------- Kernel 3 (MFMA GEMM): out[b][o][p] = b_out[o] + sum_k W'[o][k] O[pl(k)][p] --
__global__ __launch_bounds__(256, 4) void out_proj_kernel(
    const uint16_t* __restrict__ Obuf, const float* __restrict__ w_out,
    const float* __restrict__ b_out, float* __restrict__ out)
{
  __shared__ __align__(16) uint32_t As2[2][32 * RSTD];
  __shared__ __align__(16) uint16_t Wl[2][64 * WST];

  const int t    = threadIdx.x;
  const int blk  = blockIdx.x;          // 576 = 4b * 144 nt
  const int nt   = blk % 144;
  const int b    = blk / 144;
  const int n0   = nt * 64;
  const int L    = t & 63;
  const int w    = t >> 6;
  const int lcol = L & 15;
  const int lq   = L >> 4;
  const int kp_g = t >> 4;
  const int seg  = t & 15;

  const uint16_t* __restrict__ ab = Obuf + (size_t)b * 512 * VST;

  uint2  pa[2][2];
  float4 pw[4];

  auto load_chunk = [&](int k0) {
    #pragma unroll
    for (int i = 0; i < 2; ++i) {
      const int kp = kp_g + i * 16;
      const int ke = k0 + 2*kp, ko = ke + 1;
      const int pe = ((ke & 7) << 6) | (ke >> 3);
      const int po = ((ko & 7) << 6) | (ko >> 3);
      pa[i][0] = *(const uint2*)(ab + (size_t)pe * VST + n0 + seg * 4);
      pa[i][1] = *(const uint2*)(ab + (size_t)po * VST + n0 + seg * 4);
    }
    #pragma unroll
    for (int i = 0; i < 4; ++i) {
      const int idx = t + i * 256;
      pw[i] = *(const float4*)(w_out + (size_t)(idx >> 4) * 512 + k0 + (idx & 15) * 4);
    }
  };

  auto store_chunk = [&](int buf) {
    #pragma unroll
    for (int i = 0; i < 2; ++i) {
      const int kp = kp_g + i * 16;
      const uint2 a = pa[i][0], bb = pa[i][1];
      uint4 d;
      d.x = (a.x & 0xffffu) | (bb.x << 16);
      d.y = (a.x >> 16)     | (bb.x & 0xffff0000u);
      d.z = (a.y & 0xffffu) | (bb.y << 16);
      d.w = (a.y >> 16)     | (bb.y & 0xffff0000u);
      *(uint4*)&As2[buf][kp * RSTD + seg * 4] = d;
    }
    #pragma unroll
    for (int i = 0; i < 4; ++i) {
      const int idx = t + i * 256;
      const float4 v = pw[i];
      *(uint2*)&Wl[buf][(idx >> 4) * WST + (idx & 15) * 4] =
        uint2{pack2bf(v.x, v.y), pack2bf(v.z, v.w)};
    }
  };

  f32x4 acc[4];
  const f32x4 zero4 = {0.f, 0.f, 0.f, 0.f};
  #pragma unroll
  for (int tm = 0; tm < 4; ++tm) acc[tm] = zero4;

  load_chunk(0);

  for (int c = 0; c < 8; ++c) {
    const int buf = c & 1;
    store_chunk(buf);
    if (c < 7) load_chunk((c + 1) * 64);
    __syncthreads();
    #pragma unroll
    for (int ks = 0; ks < 2; ++ks) {
      u32x4 bb;
      #pragma unroll
      for (int jj = 0; jj < 4; ++jj)
        bb[jj] = As2[buf][(ks*16 + lq*4 + jj) * RSTD + w*16 + lcol];
      const bf16x8 bfr = __builtin_bit_cast(bf16x8, bb);
      #pragma unroll
      for (int tm = 0; tm < 4; ++tm) {
        const bf16x8 af = *(const bf16x8*)&Wl[buf][(tm*16 + lcol) * WST + ks*32 + lq*8];
        acc[tm] = __builtin_amdgcn_mfma_f32_16x16x32_bf16(af, bfr, acc[tm], 0, 0, 0);
      }
    }
  }

  const int p = n0 + w*16 + lcol;
  #pragma unroll
  for (int tm = 0; tm < 4; ++tm)
    #pragma unroll
    for (int r = 0; r < 4; ++r) {
      const int o = tm*16 + lq*4 + r;
      out[(size_t)(b * 64 + o) * TSS + p] = acc[tm][r] + b_out[o];
    }
}

extern "C" void kernel_launch(void* const* d_in, const int* in_sizes, int n_in,
                              void* d_out, int out_size, void* d_ws, size_t ws_size,
                              hipStream_t stream) {
  const float* x     = (const float*)d_in[0];
  const float* w_vkq = (const float*)d_in[1];
  const float* b_vkq = (const float*)d_in[2];
  const float* w_out = (const float*)d_in[3];
  const float* b_out = (const float*)d_in[4];
  float* out = (float*)d_out;

  uint16_t* Obuf = (uint16_t*)d_ws;                         // 2048*9344*2 = 38.3 MB (bf16 O)
  uint8_t*  Vr   = (uint8_t*)(Obuf + (size_t)2048 * VST);   // 3 fp8 regions, 19.4 MB each
  uint8_t*  Qr   = Vr + (size_t)2048 * VSF;
  uint8_t*  Kr   = Qr + (size_t)2048 * VSF;
  uint16_t* wbf  = (uint16_t*)(Kr + (size_t)2048 * VSF);    // 196 KB bf16 W (x32 pre-scaled)

  wcvt_kernel<<<dim3(96), dim3(256), 0, stream>>>(w_vkq, wbf);
  proj_kernel<<<dim3(2304), dim3(256), 0, stream>>>(x, wbf, b_vkq, Vr, Qr, Kr);
  attn_kernel<<<dim3(2048), dim3(384), 0, stream>>>(Vr, Qr, Kr, Obuf);
  out_proj_kernel<<<dim3(576), dim3(256), 0, stream>>>(Obuf, w_out, b_out, out);
}